// Round 8
// baseline (162.794 us; speedup 1.0000x reference)
//
#include <hip/hip_runtime.h>
#include <math.h>

#define Bsz 8
#define Cch 512
#define Npx 1024
#define TOPK 12

typedef __attribute__((ext_vector_type(8))) short bf16x8;
typedef __attribute__((ext_vector_type(4))) float f32x4;

__device__ __forceinline__ unsigned short f2bf(float x) {
    unsigned u = __float_as_uint(x);
    u += 0x7FFF + ((u >> 16) & 1);
    return (unsigned short)(u >> 16);
}
__device__ __forceinline__ float bf2f(unsigned short h) {
    return __uint_as_float(((unsigned)h) << 16);
}

// ---------------- reduction helpers (blockDim.x == 256) ----------------
__device__ __forceinline__ float warp_sum64(float v) {
    for (int o = 32; o > 0; o >>= 1) v += __shfl_down(v, o);
    return v;
}
__device__ __forceinline__ float block_sum256(float v, float* s4) {
    v = warp_sum64(v);
    int lane = threadIdx.x & 63, w = threadIdx.x >> 6;
    __syncthreads();
    if (lane == 0) s4[w] = v;
    __syncthreads();
    return s4[0] + s4[1] + s4[2] + s4[3];
}

// ---------------- 1: masked average pool (float4) ----------------
// grid (Cch, Bsz), block 256
__global__ void k_pool(const float* __restrict__ sf, const int* __restrict__ mask,
                       float* __restrict__ FPo, float* __restrict__ BPo) {
    __shared__ float s4[4];
    int c = blockIdx.x, b = blockIdx.y, t = threadIdx.x;
    const float4* f4 = (const float4*)(sf + ((size_t)b * Cch + c) * Npx);
    const int4* m4 = (const int4*)(mask + (size_t)b * Npx);
    float4 v = f4[t];
    int4 m = m4[t];
    float sumf = (m.x == 1 ? v.x : 0.f) + (m.y == 1 ? v.y : 0.f)
               + (m.z == 1 ? v.z : 0.f) + (m.w == 1 ? v.w : 0.f);
    float tot = v.x + v.y + v.z + v.w;
    float cf = (float)((m.x == 1) + (m.y == 1) + (m.z == 1) + (m.w == 1));
    sumf = block_sum256(sumf, s4);
    tot  = block_sum256(tot, s4);
    cf   = block_sum256(cf, s4);
    if (t == 0) {
        FPo[b * Cch + c] = sumf / (cf + 1e-5f);
        BPo[b * Cch + c] = (tot - sumf) / ((1024.f - cf) + 1e-5f);
    }
}

// ---------------- 2: pred logit + bf16 cast of fq tile (fused) ----------------
// grid (Npx/32, Bsz), block 256: 32 pixels/block, 8 threads/pixel (64 ch each)
__global__ void __launch_bounds__(256) k_predcast(const float* __restrict__ fq,
                       const float* __restrict__ FP, const float* __restrict__ BP,
                       float* __restrict__ dsim, float* __restrict__ invn,
                       unsigned short* __restrict__ Ft) {
    __shared__ float sFP[Cch], sBP[Cch], s4[4];
    __shared__ float rdf[8][32], rdb[8][32], rqq[8][32];
    __shared__ unsigned short S[32][522];   // stride 522: odd dword stride -> conflict-free
    int b = blockIdx.y, t = threadIdx.x;
    int tx = t & 31, ty = t >> 5;
    int p0 = blockIdx.x * 32;
    int p = p0 + tx;
    for (int c = t; c < Cch; c += 256) { sFP[c] = FP[b * Cch + c]; sBP[c] = BP[b * Cch + c]; }
    __syncthreads();
    float nf = 0.f, nb = 0.f;
    for (int c = t; c < Cch; c += 256) { nf += sFP[c] * sFP[c]; nb += sBP[c] * sBP[c]; }
    nf = sqrtf(block_sum256(nf, s4));
    nb = sqrtf(block_sum256(nb, s4));
    const float* q = fq + (size_t)b * Cch * Npx + p;
    float df = 0.f, db = 0.f, qq = 0.f;
    int c0 = ty * 64;
    #pragma unroll 4
    for (int c = 0; c < 64; c += 2) {
        float v0 = q[(size_t)(c0 + c) * Npx];
        float v1 = q[(size_t)(c0 + c + 1) * Npx];
        df += v0 * sFP[c0 + c] + v1 * sFP[c0 + c + 1];
        db += v0 * sBP[c0 + c] + v1 * sBP[c0 + c + 1];
        qq += v0 * v0 + v1 * v1;
        unsigned pk = (unsigned)f2bf(v0) | ((unsigned)f2bf(v1) << 16);
        *(unsigned*)&S[tx][c0 + c] = pk;
    }
    rdf[ty][tx] = df; rdb[ty][tx] = db; rqq[ty][tx] = qq;
    __syncthreads();
    for (int s = 4; s > 0; s >>= 1) {
        if (ty < s) {
            rdf[ty][tx] += rdf[ty + s][tx];
            rdb[ty][tx] += rdb[ty + s][tx];
            rqq[ty][tx] += rqq[ty + s][tx];
        }
        __syncthreads();
    }
    if (ty == 0) {
        float nq = sqrtf(rqq[0][tx]);
        float simf = 10.f * rdf[0][tx] / fmaxf(nq * nf, 1e-8f);
        float simb = 10.f * rdb[0][tx] / fmaxf(nq * nb, 1e-8f);
        dsim[b * Npx + p] = simf - simb;
        invn[b * Npx + p] = 1.f / nq;
    }
    int w = t >> 6, lane = t & 63;
    unsigned short* FtB = Ft + (size_t)b * Npx * Cch;
    for (int pr = w; pr < 32; pr += 4) {
        unsigned* dst = (unsigned*)(FtB + (size_t)(p0 + pr) * Cch);
        #pragma unroll
        for (int it = 0; it < 4; it++) {
            int d = it * 64 + lane;
            dst[d] = *(const unsigned*)&S[pr][d * 2];
        }
    }
}

// ---------------- 3: select + compact (fg and bg) + zero rowsum ----------------
// grid (2, Bsz), block 1024. x=0: fg, x=1: bg
__global__ void __launch_bounds__(1024) k_selcompact(const float* __restrict__ dsim,
                        const float* __restrict__ invn,
                        int* __restrict__ nsf, int* __restrict__ nsb,
                        int* __restrict__ jf, int* __restrict__ jb,
                        float* __restrict__ ivg, float* __restrict__ rowsum) {
    __shared__ int   sc[Npx];
    __shared__ float v[Npx];
    __shared__ float rv[Npx];
    __shared__ int   ri[Npx];
    __shared__ int   cnts;
    int b = blockIdx.y, t = threadIdx.x;
    bool isf = (blockIdx.x == 0);
    if (!isf) rowsum[b * Npx + t] = 0.f;   // zero-init for gram's atomics
    float d = dsim[b * Npx + t];
    float key = isf ? d : -d;
    float thres = isf ? 0.8472979f : 0.4054651f;   // ln(0.7/0.3), ln(0.6/0.4)
    int flag = (key > thres) ? 1 : 0;
    if (t == 0) cnts = 0;
    __syncthreads();
    atomicAdd(&cnts, flag);
    __syncthreads();
    if (cnts == 0) {
        v[t] = key; flag = 0;
        __syncthreads();
        for (int k = 0; k < TOPK; k++) {
            rv[t] = v[t]; ri[t] = t;
            __syncthreads();
            for (int s = 512; s > 0; s >>= 1) {
                if (t < s) {
                    float a = rv[t], bb = rv[t + s];
                    int ia = ri[t], ib = ri[t + s];
                    if (bb > a || (bb == a && ib < ia)) { rv[t] = bb; ri[t] = ib; }
                }
                __syncthreads();
            }
            int win = ri[0];
            if (t == win) { flag = 1; v[t] = -INFINITY; }
            __syncthreads();
        }
    }
    sc[t] = flag;
    __syncthreads();
    for (int off = 1; off < 1024; off <<= 1) {
        int x = (t >= off) ? sc[t - off] : 0;
        __syncthreads();
        sc[t] += x;
        __syncthreads();
    }
    if (flag) {
        int pos = sc[t] - 1;
        if (isf) jf[b * Npx + pos] = t;
        else {
            jb[b * Npx + pos] = t;
            ivg[b * Npx + pos] = invn[b * Npx + t];
        }
    }
    if (t == 1023) {
        if (isf) nsf[b] = sc[1023];
        else     nsb[b] = sc[1023];
    }
}

// ---------------- 4: prototypes via index gather ----------------
// grid (Cch/32, Bsz), block 256
__global__ void k_proto_g(const float* __restrict__ fq,
                          const int* __restrict__ jf, const int* __restrict__ nsf,
                          const int* __restrict__ jb, const int* __restrict__ nsb,
                          float* __restrict__ fgp, float* __restrict__ bgp) {
    int b = blockIdx.y, cb = blockIdx.x * 32;
    int tx = threadIdx.x & 31, ty = threadIdx.x >> 5;
    const float* F = fq + (size_t)b * Cch * Npx;
    for (int which = 0; which < 2; which++) {
        const int* ji = (which ? jb : jf) + b * Npx;
        int ns = (which ? nsb : nsf)[b];
        for (int g = 0; g < 4; g++) {
            int c = cb + g * 8 + ty;
            float s = 0.f;
            for (int k = tx; k < ns; k += 32) s += F[(size_t)c * Npx + ji[k]];
            #pragma unroll
            for (int o = 16; o > 0; o >>= 1) s += __shfl_down(s, o);
            if (tx == 0) (which ? bgp : fgp)[b * Cch + c] = s / (float)ns;
        }
    }
}

// ---------------- 5: gather+transpose selected rows -> Fg[c][jc] ----------------
// grid (32, Cch/32, Bsz), block 256
__global__ void k_gtrn(const unsigned short* __restrict__ Ft, const int* __restrict__ jb,
                       const int* __restrict__ nsb, unsigned short* __restrict__ Fg) {
    int b = blockIdx.z;
    int ns = nsb[b];
    int KC = (ns + 31) & ~31;
    int j0 = blockIdx.x * 32;
    if (j0 >= KC) return;
    int c0 = blockIdx.y * 32;
    __shared__ unsigned short tt[32][33];
    int col = threadIdx.x & 31, rr = threadIdx.x >> 5;
    const unsigned short* S = Ft + (size_t)b * Npx * Cch;
    const int* ji = jb + b * Npx;
    for (int r = rr; r < 32; r += 8) {
        int j = j0 + r;
        int src = (j < ns) ? ji[j] : ji[ns - 1];
        tt[r][col] = S[(size_t)src * Cch + c0 + col];
    }
    __syncthreads();
    unsigned short* D = Fg + (size_t)b * Cch * Npx;
    for (int r = rr; r < 32; r += 8)
        D[(size_t)(c0 + r) * Npx + j0 + col] = tt[col][r];
}

// ---------------- 6: Gram + fused exp epilogue (unnormalized softmax numerator)
// grid (8, 8, Bsz), block 256; writes exp(2*G*ivi*ivj) bf16, accumulates rowsum
__global__ void __launch_bounds__(256) k_gram_c(const unsigned short* __restrict__ Ft,
                                                const int* __restrict__ jb,
                                                const int* __restrict__ nsb,
                                                const float* __restrict__ invn,
                                                const float* __restrict__ ivg,
                                                unsigned short* __restrict__ G,
                                                float* __restrict__ rowsum) {
    int b = blockIdx.z;
    int ns = nsb[b];
    int KC = (ns + 31) & ~31;
    int j0 = blockIdx.y * 128;
    if (j0 >= KC) return;
    int i0 = blockIdx.x * 128;
    __shared__ unsigned short At[128][40];
    __shared__ unsigned short Bt[128][40];
    __shared__ int sji[128];
    __shared__ float sivI[128], sivJ[128];
    const unsigned short* FA = Ft + (size_t)b * Npx * Cch;
    int tid = threadIdx.x;
    if (tid < 128) {
        int j = j0 + tid;
        sji[tid] = (j < ns) ? jb[b * Npx + j] : jb[b * Npx];
        sivJ[tid] = ivg[b * Npx + ((j < ns) ? j : 0)];
        sivI[tid] = invn[b * Npx + i0 + tid];
    }
    __syncthreads();
    int l = tid & 63, w = tid >> 6;
    int ml = l & 15, quad = l >> 4;
    int wi = (w & 1) * 64, wj = (w >> 1) * 64;
    f32x4 acc[4][4] = {};
    for (int k0 = 0; k0 < Cch; k0 += 32) {
        #pragma unroll
        for (int s = 0; s < 2; s++) {
            int idx = tid + s * 256;
            int r = idx >> 2, kc = idx & 3;
            *(uint4*)&At[r][kc * 8] = *(const uint4*)(FA + (size_t)(i0 + r) * Cch + k0 + kc * 8);
            *(uint4*)&Bt[r][kc * 8] = *(const uint4*)(FA + (size_t)sji[r] * Cch + k0 + kc * 8);
        }
        __syncthreads();
        bf16x8 af[4], bfr[4];
        #pragma unroll
        for (int u = 0; u < 4; u++) af[u] = *(const bf16x8*)&At[wi + u * 16 + ml][quad * 8];
        #pragma unroll
        for (int v = 0; v < 4; v++) bfr[v] = *(const bf16x8*)&Bt[wj + v * 16 + ml][quad * 8];
        #pragma unroll
        for (int u = 0; u < 4; u++)
            #pragma unroll
            for (int v = 0; v < 4; v++)
                acc[u][v] = __builtin_amdgcn_mfma_f32_16x16x32_bf16(af[u], bfr[v], acc[u][v], 0, 0, 0);
        __syncthreads();
    }
    unsigned short* g = G + (size_t)b * Npx * Npx;
    float* rs = rowsum + b * Npx;
    #pragma unroll
    for (int u = 0; u < 4; u++) {
        #pragma unroll
        for (int r = 0; r < 4; r++) {
            int irow = wi + u * 16 + quad * 4 + r;
            float ivi2 = 2.f * sivI[irow];
            float rsum = 0.f;
            #pragma unroll
            for (int v = 0; v < 4; v++) {
                int jc = wj + v * 16 + ml;
                unsigned short ush = 0;
                if (j0 + jc < ns) {
                    ush = f2bf(expf(acc[u][v][r] * ivi2 * sivJ[jc]));
                    rsum += bf2f(ush);   // sum the rounded value PV will consume
                }
                g[(size_t)(i0 + irow) * Npx + j0 + jc] = ush;
            }
            #pragma unroll
            for (int o = 1; o < 16; o <<= 1) rsum += __shfl_xor(rsum, o);
            if (ml == 0) atomicAdd(&rs[i0 + irow], rsum);
        }
    }
}

// ---------------- 7: PV over compacted K -> localh (bf16, [c][i], unnormalized)
// grid (8, 8, Bsz), block 256
__global__ void __launch_bounds__(256) k_pv_c(const unsigned short* __restrict__ Fg,
                                              const unsigned short* __restrict__ A,
                                              const int* __restrict__ nsb,
                                              unsigned short* __restrict__ Dout) {
    int b = blockIdx.z;
    int KC = (nsb[b] + 31) & ~31;
    __shared__ unsigned short At[64][40];
    __shared__ unsigned short Bt[128][40];
    int i0 = blockIdx.x * 128, c0 = blockIdx.y * 64;
    const unsigned short* F = Fg + (size_t)b * Cch * Npx;
    const unsigned short* Ar = A + (size_t)b * Npx * Npx;
    int tid = threadIdx.x;
    int l = tid & 63, w = tid >> 6;
    int ml = l & 15, quad = l >> 4;
    int wm = (w & 1) * 32, wn = (w >> 1) * 64;
    f32x4 acc[2][4] = {};
    for (int j0 = 0; j0 < KC; j0 += 32) {
        {
            int r = tid >> 2, kc = tid & 3;
            *(uint4*)&At[r][kc * 8] = *(const uint4*)(F + (size_t)(c0 + r) * Npx + j0 + kc * 8);
        }
        #pragma unroll
        for (int s = 0; s < 2; s++) {
            int idx = tid + s * 256;
            int r = idx >> 2, kc = idx & 3;
            *(uint4*)&Bt[r][kc * 8] = *(const uint4*)(Ar + (size_t)(i0 + r) * Npx + j0 + kc * 8);
        }
        __syncthreads();
        bf16x8 af[2], bfr[4];
        #pragma unroll
        for (int u = 0; u < 2; u++) af[u] = *(const bf16x8*)&At[wm + u * 16 + ml][quad * 8];
        #pragma unroll
        for (int v = 0; v < 4; v++) bfr[v] = *(const bf16x8*)&Bt[wn + v * 16 + ml][quad * 8];
        #pragma unroll
        for (int u = 0; u < 2; u++)
            #pragma unroll
            for (int v = 0; v < 4; v++)
                acc[u][v] = __builtin_amdgcn_mfma_f32_16x16x32_bf16(af[u], bfr[v], acc[u][v], 0, 0, 0);
        __syncthreads();
    }
    unsigned short* D = Dout + (size_t)b * Cch * Npx;
    #pragma unroll
    for (int u = 0; u < 2; u++) {
        int c = c0 + wm + u * 16 + quad * 4;
        #pragma unroll
        for (int v = 0; v < 4; v++) {
            int i = i0 + wn + v * 16 + ml;
            #pragma unroll
            for (int r = 0; r < 4; r++)
                D[(size_t)(c + r) * Npx + i] = f2bf(acc[u][v][r]);
        }
    }
}

// ---------------- 8: final dual similarity (normalization folded in) ----------------
// grid (Npx/32, Bsz), block 256
__global__ void k_out(const unsigned short* __restrict__ Ft, const float* __restrict__ FP,
                      const float* __restrict__ fgp, const float* __restrict__ bgp,
                      const unsigned short* __restrict__ localh,
                      const float* __restrict__ rowsum, float* __restrict__ out) {
    __shared__ float sFP1[Cch], sBG[Cch], s4[4];
    __shared__ float rdf[8][32], rdb[8][32], rqq[8][32], rnb[8][32];
    int b = blockIdx.y, t = threadIdx.x;
    int tx = t & 31, ty = t >> 5;
    int p = blockIdx.x * 32 + tx;
    for (int c = t; c < Cch; c += 256) {
        sFP1[c] = 0.5f * FP[b * Cch + c] + 0.5f * fgp[b * Cch + c];
        sBG[c] = 0.3f * bgp[b * Cch + c];
    }
    __syncthreads();
    float nf = 0.f;
    for (int c = t; c < Cch; c += 256) nf += sFP1[c] * sFP1[c];
    nf = sqrtf(block_sum256(nf, s4));
    const unsigned short* qr = Ft + ((size_t)b * Npx + p) * Cch;
    const unsigned short* lo = localh + (size_t)b * Cch * Npx + p;
    float wz = 0.7f / rowsum[b * Npx + p];   // fold softmax normalization here
    float df = 0.f, db = 0.f, qq = 0.f, nb2 = 0.f;
    int c0 = ty * 64;
    #pragma unroll
    for (int cc = 0; cc < 8; cc++) {
        bf16x8 qv = *(const bf16x8*)&qr[c0 + cc * 8];
        #pragma unroll
        for (int e = 0; e < 8; e++) {
            int c = c0 + cc * 8 + e;
            float v = bf2f((unsigned short)qv[e]);
            float bp1 = sBG[c] + wz * bf2f(lo[(size_t)c * Npx]);
            df += v * sFP1[c];
            db += v * bp1;
            qq += v * v;
            nb2 += bp1 * bp1;
        }
    }
    rdf[ty][tx] = df; rdb[ty][tx] = db; rqq[ty][tx] = qq; rnb[ty][tx] = nb2;
    __syncthreads();
    for (int s = 4; s > 0; s >>= 1) {
        if (ty < s) {
            rdf[ty][tx] += rdf[ty + s][tx];
            rdb[ty][tx] += rdb[ty + s][tx];
            rqq[ty][tx] += rqq[ty + s][tx];
            rnb[ty][tx] += rnb[ty + s][tx];
        }
        __syncthreads();
    }
    if (ty == 0) {
        float nq = sqrtf(rqq[0][tx]);
        float sf = 10.f * rdf[0][tx] / fmaxf(nq * nf, 1e-8f);
        float sb = 10.f * rdb[0][tx] / fmaxf(nq * sqrtf(rnb[0][tx]), 1e-8f);
        out[((size_t)b * 2) * Npx + p] = sb;
        out[((size_t)b * 2 + 1) * Npx + p] = sf;
    }
}

extern "C" void kernel_launch(void* const* d_in, const int* in_sizes, int n_in,
                              void* d_out, int out_size, void* d_ws, size_t ws_size,
                              hipStream_t stream) {
    const float* fq = (const float*)d_in[0];
    const float* sf = (const float*)d_in[1];
    const int* mask = (const int*)d_in[2];
    float* out = (float*)d_out;

    float* ws = (float*)d_ws;
    float* FP     = ws;                        // B*C
    float* BP     = FP + Bsz * Cch;
    float* fgp    = BP + Bsz * Cch;
    float* bgp    = fgp + Bsz * Cch;
    float* dsim   = bgp + Bsz * Cch;           // B*N
    float* invn   = dsim + Bsz * Npx;
    float* ivg    = invn + Bsz * Npx;
    float* rowsum = ivg + Bsz * Npx;           // B*N softmax denominators
    int*   nsf    = (int*)(rowsum + Bsz * Npx);
    int*   nsb    = nsf + 8;
    int*   jf     = nsb + 8;                   // B*N
    int*   jb     = jf + Bsz * Npx;            // B*N
    unsigned short* Ft     = (unsigned short*)(jb + Bsz * Npx);          // 8 MB [i][c]
    unsigned short* Fg     = Ft + (size_t)Bsz * Npx * Cch;               // 8 MB [c][jc]
    unsigned short* Gb     = Fg + (size_t)Bsz * Cch * Npx;               // 16 MB
    unsigned short* localh = Gb + (size_t)Bsz * Npx * Npx;               // 8 MB bf16 [c][i]

    k_pool<<<dim3(Cch, Bsz), 256, 0, stream>>>(sf, mask, FP, BP);
    k_predcast<<<dim3(Npx / 32, Bsz), 256, 0, stream>>>(fq, FP, BP, dsim, invn, Ft);
    k_selcompact<<<dim3(2, Bsz), 1024, 0, stream>>>(dsim, invn, nsf, nsb, jf, jb, ivg, rowsum);
    k_proto_g<<<dim3(Cch / 32, Bsz), 256, 0, stream>>>(fq, jf, nsf, jb, nsb, fgp, bgp);
    k_gtrn<<<dim3(32, Cch / 32, Bsz), 256, 0, stream>>>(Ft, jb, nsb, Fg);
    k_gram_c<<<dim3(8, 8, Bsz), 256, 0, stream>>>(Ft, jb, nsb, invn, ivg, Gb, rowsum);
    k_pv_c<<<dim3(8, 8, Bsz), 256, 0, stream>>>(Fg, Gb, nsb, localh);
    k_out<<<dim3(Npx / 32, Bsz), 256, 0, stream>>>(Ft, FP, fgp, bgp, localh, rowsum, out);
}

// Round 9
// 155.816 us; speedup vs baseline: 1.0448x; 1.0448x over previous
//
#include <hip/hip_runtime.h>
#include <math.h>

#define Bsz 8
#define Cch 512
#define Npx 1024
#define TOPK 12

typedef __attribute__((ext_vector_type(8))) short bf16x8;
typedef __attribute__((ext_vector_type(4))) float f32x4;

__device__ __forceinline__ unsigned short f2bf(float x) {
    unsigned u = __float_as_uint(x);
    u += 0x7FFF + ((u >> 16) & 1);
    return (unsigned short)(u >> 16);
}
__device__ __forceinline__ float bf2f(unsigned short h) {
    return __uint_as_float(((unsigned)h) << 16);
}

// ---------------- reduction helpers (blockDim.x == 256) ----------------
__device__ __forceinline__ float warp_sum64(float v) {
    for (int o = 32; o > 0; o >>= 1) v += __shfl_down(v, o);
    return v;
}
__device__ __forceinline__ float block_sum256(float v, float* s4) {
    v = warp_sum64(v);
    int lane = threadIdx.x & 63, w = threadIdx.x >> 6;
    __syncthreads();
    if (lane == 0) s4[w] = v;
    __syncthreads();
    return s4[0] + s4[1] + s4[2] + s4[3];
}

// ---------------- 1: masked average pool (float4) ----------------
// grid (Cch, Bsz), block 256
__global__ void k_pool(const float* __restrict__ sf, const int* __restrict__ mask,
                       float* __restrict__ FPo, float* __restrict__ BPo) {
    __shared__ float s4[4];
    int c = blockIdx.x, b = blockIdx.y, t = threadIdx.x;
    const float4* f4 = (const float4*)(sf + ((size_t)b * Cch + c) * Npx);
    const int4* m4 = (const int4*)(mask + (size_t)b * Npx);
    float4 v = f4[t];
    int4 m = m4[t];
    float sumf = (m.x == 1 ? v.x : 0.f) + (m.y == 1 ? v.y : 0.f)
               + (m.z == 1 ? v.z : 0.f) + (m.w == 1 ? v.w : 0.f);
    float tot = v.x + v.y + v.z + v.w;
    float cf = (float)((m.x == 1) + (m.y == 1) + (m.z == 1) + (m.w == 1));
    sumf = block_sum256(sumf, s4);
    tot  = block_sum256(tot, s4);
    cf   = block_sum256(cf, s4);
    if (t == 0) {
        FPo[b * Cch + c] = sumf / (cf + 1e-5f);
        BPo[b * Cch + c] = (tot - sumf) / ((1024.f - cf) + 1e-5f);
    }
}

// ---------------- 2: pred logit + bf16 cast of fq tile (fused) ----------------
// grid (Npx/32, Bsz), block 256
__global__ void __launch_bounds__(256) k_predcast(const float* __restrict__ fq,
                       const float* __restrict__ FP, const float* __restrict__ BP,
                       float* __restrict__ dsim, float* __restrict__ invn,
                       unsigned short* __restrict__ Ft) {
    __shared__ float sFP[Cch], sBP[Cch], s4[4];
    __shared__ float rdf[8][32], rdb[8][32], rqq[8][32];
    __shared__ unsigned short S[32][522];   // odd dword stride -> conflict-free
    int b = blockIdx.y, t = threadIdx.x;
    int tx = t & 31, ty = t >> 5;
    int p0 = blockIdx.x * 32;
    int p = p0 + tx;
    for (int c = t; c < Cch; c += 256) { sFP[c] = FP[b * Cch + c]; sBP[c] = BP[b * Cch + c]; }
    __syncthreads();
    float nf = 0.f, nb = 0.f;
    for (int c = t; c < Cch; c += 256) { nf += sFP[c] * sFP[c]; nb += sBP[c] * sBP[c]; }
    nf = sqrtf(block_sum256(nf, s4));
    nb = sqrtf(block_sum256(nb, s4));
    const float* q = fq + (size_t)b * Cch * Npx + p;
    float df = 0.f, db = 0.f, qq = 0.f;
    int c0 = ty * 64;
    #pragma unroll 4
    for (int c = 0; c < 64; c += 2) {
        float v0 = q[(size_t)(c0 + c) * Npx];
        float v1 = q[(size_t)(c0 + c + 1) * Npx];
        df += v0 * sFP[c0 + c] + v1 * sFP[c0 + c + 1];
        db += v0 * sBP[c0 + c] + v1 * sBP[c0 + c + 1];
        qq += v0 * v0 + v1 * v1;
        unsigned pk = (unsigned)f2bf(v0) | ((unsigned)f2bf(v1) << 16);
        *(unsigned*)&S[tx][c0 + c] = pk;
    }
    rdf[ty][tx] = df; rdb[ty][tx] = db; rqq[ty][tx] = qq;
    __syncthreads();
    for (int s = 4; s > 0; s >>= 1) {
        if (ty < s) {
            rdf[ty][tx] += rdf[ty + s][tx];
            rdb[ty][tx] += rdb[ty + s][tx];
            rqq[ty][tx] += rqq[ty + s][tx];
        }
        __syncthreads();
    }
    if (ty == 0) {
        float nq = sqrtf(rqq[0][tx]);
        float simf = 10.f * rdf[0][tx] / fmaxf(nq * nf, 1e-8f);
        float simb = 10.f * rdb[0][tx] / fmaxf(nq * nb, 1e-8f);
        dsim[b * Npx + p] = simf - simb;
        invn[b * Npx + p] = 1.f / nq;
    }
    int w = t >> 6, lane = t & 63;
    unsigned short* FtB = Ft + (size_t)b * Npx * Cch;
    for (int pr = w; pr < 32; pr += 4) {
        unsigned* dst = (unsigned*)(FtB + (size_t)(p0 + pr) * Cch);
        #pragma unroll
        for (int it = 0; it < 4; it++) {
            int d = it * 64 + lane;
            dst[d] = *(const unsigned*)&S[pr][d * 2];
        }
    }
}

// ---------------- 3: select + compact, wave-shfl scan ----------------
// grid (2, Bsz), block 1024 (16 waves). x=0: fg, x=1: bg
__global__ void __launch_bounds__(1024) k_selcompact(const float* __restrict__ dsim,
                        const float* __restrict__ invn,
                        int* __restrict__ nsf, int* __restrict__ nsb,
                        int* __restrict__ jf, int* __restrict__ jb,
                        float* __restrict__ ivg) {
    __shared__ int wsum[16];
    int b = blockIdx.y, t = threadIdx.x;
    int lane = t & 63, w = t >> 6;
    bool isf = (blockIdx.x == 0);
    float d = dsim[b * Npx + t];
    float key = isf ? d : -d;
    float thres = isf ? 0.8472979f : 0.4054651f;   // ln(0.7/0.3), ln(0.6/0.4)
    int flag = (key > thres) ? 1 : 0;
    // fast path: wave inclusive scan + wave-total combine (2 barriers)
    int x = flag;
    #pragma unroll
    for (int o = 1; o < 64; o <<= 1) {
        int y = __shfl_up(x, o);
        if (lane >= o) x += y;
    }
    if (lane == 63) wsum[w] = x;
    __syncthreads();
    int base = 0, total = 0;
    #pragma unroll
    for (int k = 0; k < 16; k++) {
        int s = wsum[k];
        if (k < w) base += s;
        total += s;
    }
    if (total == 0) {
        // fallback: top-12 (lower index wins ties), then naive rescan — cold path
        __shared__ int   sc[Npx];
        __shared__ float v[Npx];
        __shared__ float rv[Npx];
        __shared__ int   ri[Npx];
        v[t] = key; flag = 0;
        __syncthreads();
        for (int k = 0; k < TOPK; k++) {
            rv[t] = v[t]; ri[t] = t;
            __syncthreads();
            for (int s = 512; s > 0; s >>= 1) {
                if (t < s) {
                    float a = rv[t], bb = rv[t + s];
                    int ia = ri[t], ib = ri[t + s];
                    if (bb > a || (bb == a && ib < ia)) { rv[t] = bb; ri[t] = ib; }
                }
                __syncthreads();
            }
            int win = ri[0];
            if (t == win) { flag = 1; v[t] = -INFINITY; }
            __syncthreads();
        }
        sc[t] = flag;
        __syncthreads();
        for (int off = 1; off < 1024; off <<= 1) {
            int xx = (t >= off) ? sc[t - off] : 0;
            __syncthreads();
            sc[t] += xx;
            __syncthreads();
        }
        if (flag) {
            int pos = sc[t] - 1;
            if (isf) jf[b * Npx + pos] = t;
            else {
                jb[b * Npx + pos] = t;
                ivg[b * Npx + pos] = invn[b * Npx + t];
            }
        }
        if (t == 1023) { if (isf) nsf[b] = sc[1023]; else nsb[b] = sc[1023]; }
        return;
    }
    if (flag) {
        int pos = base + x - 1;
        if (isf) jf[b * Npx + pos] = t;
        else {
            jb[b * Npx + pos] = t;
            ivg[b * Npx + pos] = invn[b * Npx + t];
        }
    }
    if (t == 0) { if (isf) nsf[b] = total; else nsb[b] = total; }
}

// ---------------- 4: fused prototypes + gather-transpose ----------------
// grid (32, 17, Bsz), block 256.
//   y < 16 : gtrn tile  (j0 = x*32, c0 = y*32)  -> Fg[c][jc]
//   y == 16: prototypes (cb = x*32, x < 16)
__global__ void k_mid(const float* __restrict__ fq, const unsigned short* __restrict__ Ft,
                      const int* __restrict__ jf, const int* __restrict__ nsf,
                      const int* __restrict__ jb, const int* __restrict__ nsb,
                      unsigned short* __restrict__ Fg,
                      float* __restrict__ fgp, float* __restrict__ bgp) {
    int b = blockIdx.z;
    if (blockIdx.y < 16) {
        int ns = nsb[b];
        int KC = (ns + 31) & ~31;
        int j0 = blockIdx.x * 32;
        if (j0 >= KC) return;
        int c0 = blockIdx.y * 32;
        __shared__ unsigned short tt[32][33];
        int col = threadIdx.x & 31, rr = threadIdx.x >> 5;
        const unsigned short* S = Ft + (size_t)b * Npx * Cch;
        const int* ji = jb + b * Npx;
        for (int r = rr; r < 32; r += 8) {
            int j = j0 + r;
            int src = (j < ns) ? ji[j] : ji[ns - 1];   // pad rows: P==0 there
            tt[r][col] = S[(size_t)src * Cch + c0 + col];
        }
        __syncthreads();
        unsigned short* D = Fg + (size_t)b * Cch * Npx;
        for (int r = rr; r < 32; r += 8)
            D[(size_t)(c0 + r) * Npx + j0 + col] = tt[col][r];
    } else {
        if (blockIdx.x >= 16) return;
        int cb = blockIdx.x * 32;
        int tx = threadIdx.x & 31, ty = threadIdx.x >> 5;
        const float* F = fq + (size_t)b * Cch * Npx;
        for (int which = 0; which < 2; which++) {
            const int* ji = (which ? jb : jf) + b * Npx;
            int ns = (which ? nsb : nsf)[b];
            for (int g = 0; g < 4; g++) {
                int c = cb + g * 8 + ty;
                float s = 0.f;
                for (int k = tx; k < ns; k += 32) s += F[(size_t)c * Npx + ji[k]];
                #pragma unroll
                for (int o = 16; o > 0; o >>= 1) s += __shfl_down(s, o);
                if (tx == 0) (which ? bgp : fgp)[b * Cch + c] = s / (float)ns;
            }
        }
    }
}

// ---------------- 5: Gram over compacted columns (inline index gather) --------
// grid (8, 8, Bsz), block 256; j-tiles beyond KC exit
__global__ void __launch_bounds__(256) k_gram_c(const unsigned short* __restrict__ Ft,
                                                const int* __restrict__ jb,
                                                const int* __restrict__ nsb,
                                                unsigned short* __restrict__ G) {
    int b = blockIdx.z;
    int ns = nsb[b];
    int KC = (ns + 31) & ~31;
    int j0 = blockIdx.y * 128;
    if (j0 >= KC) return;
    int i0 = blockIdx.x * 128;
    __shared__ unsigned short At[128][40];
    __shared__ unsigned short Bt[128][40];
    __shared__ int sji[128];
    const unsigned short* FA = Ft + (size_t)b * Npx * Cch;
    int tid = threadIdx.x;
    if (tid < 128) {
        int j = j0 + tid;
        sji[tid] = (j < ns) ? jb[b * Npx + j] : jb[b * Npx];
    }
    __syncthreads();
    int l = tid & 63, w = tid >> 6;
    int ml = l & 15, quad = l >> 4;
    int wi = (w & 1) * 64, wj = (w >> 1) * 64;
    f32x4 acc[4][4] = {};
    for (int k0 = 0; k0 < Cch; k0 += 32) {
        #pragma unroll
        for (int s = 0; s < 2; s++) {
            int idx = tid + s * 256;
            int r = idx >> 2, kc = idx & 3;
            *(uint4*)&At[r][kc * 8] = *(const uint4*)(FA + (size_t)(i0 + r) * Cch + k0 + kc * 8);
            *(uint4*)&Bt[r][kc * 8] = *(const uint4*)(FA + (size_t)sji[r] * Cch + k0 + kc * 8);
        }
        __syncthreads();
        bf16x8 af[4], bfr[4];
        #pragma unroll
        for (int u = 0; u < 4; u++) af[u] = *(const bf16x8*)&At[wi + u * 16 + ml][quad * 8];
        #pragma unroll
        for (int v = 0; v < 4; v++) bfr[v] = *(const bf16x8*)&Bt[wj + v * 16 + ml][quad * 8];
        #pragma unroll
        for (int u = 0; u < 4; u++)
            #pragma unroll
            for (int v = 0; v < 4; v++)
                acc[u][v] = __builtin_amdgcn_mfma_f32_16x16x32_bf16(af[u], bfr[v], acc[u][v], 0, 0, 0);
        __syncthreads();
    }
    unsigned short* g = G + (size_t)b * Npx * Npx;
    #pragma unroll
    for (int u = 0; u < 4; u++) {
        int i = i0 + wi + u * 16 + quad * 4;
        #pragma unroll
        for (int v = 0; v < 4; v++) {
            int j = j0 + wj + v * 16 + ml;
            #pragma unroll
            for (int r = 0; r < 4; r++)
                g[(size_t)(i + r) * Npx + j] = f2bf(acc[u][v][r]);
        }
    }
}

// ---------------- 6: wave-per-row compact softmax (no max pass) ----------------
// grid (Npx/4, Bsz), block 256 (4 waves, one row each)
__global__ void k_softmax_w(unsigned short* __restrict__ G, const float* __restrict__ invn,
                            const float* __restrict__ ivg, const int* __restrict__ nsb) {
    int b = blockIdx.y;
    int ns = nsb[b];
    int KC = (ns + 31) & ~31;
    int w = threadIdx.x >> 6, l = threadIdx.x & 63;
    int i = blockIdx.x * 4 + w;
    unsigned short* row = G + ((size_t)b * Npx + i) * Npx;
    const float* iv = ivg + (size_t)b * Npx;
    float ivi = 2.f * invn[b * Npx + i];
    float vals[16];
    float sum = 0.f;
    #pragma unroll
    for (int k = 0; k < 16; k++) {
        int jc = k * 64 + l;
        float e = 0.f;
        if (jc < ns) e = expf(bf2f(row[jc]) * ivi * iv[jc]);
        vals[k] = e;
        sum += e;
    }
    #pragma unroll
    for (int o = 32; o > 0; o >>= 1) sum += __shfl_xor(sum, o);
    float inv = 1.f / sum;
    #pragma unroll
    for (int k = 0; k < 16; k++) {
        int jc = k * 64 + l;
        if (jc < KC) row[jc] = f2bf(vals[k] * inv);   // [ns,KC) -> 0
    }
}

// ---------------- 7: PV over compacted K -> localh (bf16, [c][i]) ----------------
// grid (8, 8, Bsz), block 256
__global__ void __launch_bounds__(256) k_pv_c(const unsigned short* __restrict__ Fg,
                                              const unsigned short* __restrict__ A,
                                              const int* __restrict__ nsb,
                                              unsigned short* __restrict__ Dout) {
    int b = blockIdx.z;
    int KC = (nsb[b] + 31) & ~31;
    __shared__ unsigned short At[64][40];
    __shared__ unsigned short Bt[128][40];
    int i0 = blockIdx.x * 128, c0 = blockIdx.y * 64;
    const unsigned short* F = Fg + (size_t)b * Cch * Npx;
    const unsigned short* Ar = A + (size_t)b * Npx * Npx;
    int tid = threadIdx.x;
    int l = tid & 63, w = tid >> 6;
    int ml = l & 15, quad = l >> 4;
    int wm = (w & 1) * 32, wn = (w >> 1) * 64;
    f32x4 acc[2][4] = {};
    for (int j0 = 0; j0 < KC; j0 += 32) {
        {
            int r = tid >> 2, kc = tid & 3;
            *(uint4*)&At[r][kc * 8] = *(const uint4*)(F + (size_t)(c0 + r) * Npx + j0 + kc * 8);
        }
        #pragma unroll
        for (int s = 0; s < 2; s++) {
            int idx = tid + s * 256;
            int r = idx >> 2, kc = idx & 3;
            *(uint4*)&Bt[r][kc * 8] = *(const uint4*)(Ar + (size_t)(i0 + r) * Npx + j0 + kc * 8);
        }
        __syncthreads();
        bf16x8 af[2], bfr[4];
        #pragma unroll
        for (int u = 0; u < 2; u++) af[u] = *(const bf16x8*)&At[wm + u * 16 + ml][quad * 8];
        #pragma unroll
        for (int v = 0; v < 4; v++) bfr[v] = *(const bf16x8*)&Bt[wn + v * 16 + ml][quad * 8];
        #pragma unroll
        for (int u = 0; u < 2; u++)
            #pragma unroll
            for (int v = 0; v < 4; v++)
                acc[u][v] = __builtin_amdgcn_mfma_f32_16x16x32_bf16(af[u], bfr[v], acc[u][v], 0, 0, 0);
        __syncthreads();
    }
    unsigned short* D = Dout + (size_t)b * Cch * Npx;
    #pragma unroll
    for (int u = 0; u < 2; u++) {
        int c = c0 + wm + u * 16 + quad * 4;
        #pragma unroll
        for (int v = 0; v < 4; v++) {
            int i = i0 + wn + v * 16 + ml;
            #pragma unroll
            for (int r = 0; r < 4; r++)
                D[(size_t)(c + r) * Npx + i] = f2bf(acc[u][v][r]);
        }
    }
}

// ---------------- 8: final dual similarity (q from bf16 Ft rows) ----------------
// grid (Npx/32, Bsz), block 256
__global__ void k_out(const unsigned short* __restrict__ Ft, const float* __restrict__ FP,
                      const float* __restrict__ fgp, const float* __restrict__ bgp,
                      const unsigned short* __restrict__ localh, float* __restrict__ out) {
    __shared__ float sFP1[Cch], sBG[Cch], s4[4];
    __shared__ float rdf[8][32], rdb[8][32], rqq[8][32], rnb[8][32];
    int b = blockIdx.y, t = threadIdx.x;
    int tx = t & 31, ty = t >> 5;
    int p = blockIdx.x * 32 + tx;
    for (int c = t; c < Cch; c += 256) {
        sFP1[c] = 0.5f * FP[b * Cch + c] + 0.5f * fgp[b * Cch + c];
        sBG[c] = 0.3f * bgp[b * Cch + c];
    }
    __syncthreads();
    float nf = 0.f;
    for (int c = t; c < Cch; c += 256) nf += sFP1[c] * sFP1[c];
    nf = sqrtf(block_sum256(nf, s4));
    const unsigned short* qr = Ft + ((size_t)b * Npx + p) * Cch;
    const unsigned short* lo = localh + (size_t)b * Cch * Npx + p;
    float df = 0.f, db = 0.f, qq = 0.f, nb2 = 0.f;
    int c0 = ty * 64;
    #pragma unroll
    for (int cc = 0; cc < 8; cc++) {
        bf16x8 qv = *(const bf16x8*)&qr[c0 + cc * 8];
        #pragma unroll
        for (int e = 0; e < 8; e++) {
            int c = c0 + cc * 8 + e;
            float v = bf2f((unsigned short)qv[e]);
            float bp1 = sBG[c] + 0.7f * bf2f(lo[(size_t)c * Npx]);
            df += v * sFP1[c];
            db += v * bp1;
            qq += v * v;
            nb2 += bp1 * bp1;
        }
    }
    rdf[ty][tx] = df; rdb[ty][tx] = db; rqq[ty][tx] = qq; rnb[ty][tx] = nb2;
    __syncthreads();
    for (int s = 4; s > 0; s >>= 1) {
        if (ty < s) {
            rdf[ty][tx] += rdf[ty + s][tx];
            rdb[ty][tx] += rdb[ty + s][tx];
            rqq[ty][tx] += rqq[ty + s][tx];
            rnb[ty][tx] += rnb[ty + s][tx];
        }
        __syncthreads();
    }
    if (ty == 0) {
        float nq = sqrtf(rqq[0][tx]);
        float sf = 10.f * rdf[0][tx] / fmaxf(nq * nf, 1e-8f);
        float sb = 10.f * rdb[0][tx] / fmaxf(nq * sqrtf(rnb[0][tx]), 1e-8f);
        out[((size_t)b * 2) * Npx + p] = sb;
        out[((size_t)b * 2 + 1) * Npx + p] = sf;
    }
}

extern "C" void kernel_launch(void* const* d_in, const int* in_sizes, int n_in,
                              void* d_out, int out_size, void* d_ws, size_t ws_size,
                              hipStream_t stream) {
    const float* fq = (const float*)d_in[0];
    const float* sf = (const float*)d_in[1];
    const int* mask = (const int*)d_in[2];
    float* out = (float*)d_out;

    float* ws = (float*)d_ws;
    float* FP    = ws;                        // B*C
    float* BP    = FP + Bsz * Cch;
    float* fgp   = BP + Bsz * Cch;
    float* bgp   = fgp + Bsz * Cch;
    float* dsim  = bgp + Bsz * Cch;           // B*N
    float* invn  = dsim + Bsz * Npx;
    float* ivg   = invn + Bsz * Npx;
    int*   nsf   = (int*)(ivg + Bsz * Npx);   // 8
    int*   nsb   = nsf + 8;                   // 8
    int*   jf    = nsb + 8;                   // B*N
    int*   jb    = jf + Bsz * Npx;            // B*N
    unsigned short* Ft     = (unsigned short*)(jb + Bsz * Npx);          // 8 MB [i][c]
    unsigned short* Fg     = Ft + (size_t)Bsz * Npx * Cch;               // 8 MB [c][jc]
    unsigned short* Gb     = Fg + (size_t)Bsz * Cch * Npx;               // 16 MB
    unsigned short* localh = Gb + (size_t)Bsz * Npx * Npx;               // 8 MB bf16 [c][i]

    k_pool<<<dim3(Cch, Bsz), 256, 0, stream>>>(sf, mask, FP, BP);
    k_predcast<<<dim3(Npx / 32, Bsz), 256, 0, stream>>>(fq, FP, BP, dsim, invn, Ft);
    k_selcompact<<<dim3(2, Bsz), 1024, 0, stream>>>(dsim, invn, nsf, nsb, jf, jb, ivg);
    k_mid<<<dim3(32, 17, Bsz), 256, 0, stream>>>(fq, Ft, jf, nsf, jb, nsb, Fg, fgp, bgp);
    k_gram_c<<<dim3(8, 8, Bsz), 256, 0, stream>>>(Ft, jb, nsb, Gb);
    k_softmax_w<<<dim3(Npx / 4, Bsz), 256, 0, stream>>>(Gb, invn, ivg, nsb);
    k_pv_c<<<dim3(8, 8, Bsz), 256, 0, stream>>>(Fg, Gb, nsb, localh);
    k_out<<<dim3(Npx / 32, Bsz), 256, 0, stream>>>(Ft, FP, fgp, bgp, localh, out);
}

// Round 10
// 153.268 us; speedup vs baseline: 1.0622x; 1.0166x over previous
//
#include <hip/hip_runtime.h>
#include <math.h>

#define Bsz 8
#define Cch 512
#define Npx 1024
#define TOPK 12

typedef __attribute__((ext_vector_type(8))) short bf16x8;
typedef __attribute__((ext_vector_type(4))) float f32x4;

__device__ __forceinline__ unsigned short f2bf(float x) {
    unsigned u = __float_as_uint(x);
    u += 0x7FFF + ((u >> 16) & 1);
    return (unsigned short)(u >> 16);
}
__device__ __forceinline__ float bf2f(unsigned short h) {
    return __uint_as_float(((unsigned)h) << 16);
}

// ---------------- reduction helpers ----------------
__device__ __forceinline__ float warp_sum64(float v) {
    for (int o = 32; o > 0; o >>= 1) v += __shfl_down(v, o);
    return v;
}
__device__ __forceinline__ float block_sum256(float v, float* s4) {
    v = warp_sum64(v);
    int lane = threadIdx.x & 63, w = threadIdx.x >> 6;
    __syncthreads();
    if (lane == 0) s4[w] = v;
    __syncthreads();
    return s4[0] + s4[1] + s4[2] + s4[3];
}
__device__ __forceinline__ float block_sum512(float v, float* s8) {
    v = warp_sum64(v);
    int lane = threadIdx.x & 63, w = threadIdx.x >> 6;
    __syncthreads();
    if (lane == 0) s8[w] = v;
    __syncthreads();
    float r = 0.f;
    #pragma unroll
    for (int k = 0; k < 8; k++) r += s8[k];
    return r;
}

// ---------------- 1: masked average pool (float4) ----------------
// grid (Cch, Bsz), block 256
__global__ void k_pool(const float* __restrict__ sf, const int* __restrict__ mask,
                       float* __restrict__ FPo, float* __restrict__ BPo) {
    __shared__ float s4[4];
    int c = blockIdx.x, b = blockIdx.y, t = threadIdx.x;
    const float4* f4 = (const float4*)(sf + ((size_t)b * Cch + c) * Npx);
    const int4* m4 = (const int4*)(mask + (size_t)b * Npx);
    float4 v = f4[t];
    int4 m = m4[t];
    float sumf = (m.x == 1 ? v.x : 0.f) + (m.y == 1 ? v.y : 0.f)
               + (m.z == 1 ? v.z : 0.f) + (m.w == 1 ? v.w : 0.f);
    float tot = v.x + v.y + v.z + v.w;
    float cf = (float)((m.x == 1) + (m.y == 1) + (m.z == 1) + (m.w == 1));
    sumf = block_sum256(sumf, s4);
    tot  = block_sum256(tot, s4);
    cf   = block_sum256(cf, s4);
    if (t == 0) {
        FPo[b * Cch + c] = sumf / (cf + 1e-5f);
        BPo[b * Cch + c] = (tot - sumf) / ((1024.f - cf) + 1e-5f);
    }
}

// ---------------- 2: pred logit + bf16 cast (block 512: 16 thr/pixel) ---------
// grid (Npx/32, Bsz), block 512: 32 pixels/block, 16 threads/pixel (32 ch each)
__global__ void __launch_bounds__(512) k_predcast(const float* __restrict__ fq,
                       const float* __restrict__ FP, const float* __restrict__ BP,
                       float* __restrict__ dsim, float* __restrict__ invn,
                       unsigned short* __restrict__ Ft) {
    __shared__ float sFP[Cch], sBP[Cch], s8[8];
    __shared__ float rdf[16][32], rdb[16][32], rqq[16][32];
    __shared__ unsigned short S[32][522];   // odd dword stride -> conflict-free
    int b = blockIdx.y, t = threadIdx.x;
    int tx = t & 31, ty = t >> 5;           // ty in [0,16)
    int p0 = blockIdx.x * 32;
    int p = p0 + tx;
    sFP[t] = FP[b * Cch + t];
    sBP[t] = BP[b * Cch + t];
    __syncthreads();
    float nf = sqrtf(block_sum512(sFP[t] * sFP[t], s8));
    float nb = sqrtf(block_sum512(sBP[t] * sBP[t], s8));
    const float* q = fq + (size_t)b * Cch * Npx + p;
    float df = 0.f, db = 0.f, qq = 0.f;
    int c0 = ty * 32;
    #pragma unroll 4
    for (int c = 0; c < 32; c += 2) {
        float v0 = q[(size_t)(c0 + c) * Npx];
        float v1 = q[(size_t)(c0 + c + 1) * Npx];
        df += v0 * sFP[c0 + c] + v1 * sFP[c0 + c + 1];
        db += v0 * sBP[c0 + c] + v1 * sBP[c0 + c + 1];
        qq += v0 * v0 + v1 * v1;
        unsigned pk = (unsigned)f2bf(v0) | ((unsigned)f2bf(v1) << 16);
        *(unsigned*)&S[tx][c0 + c] = pk;
    }
    rdf[ty][tx] = df; rdb[ty][tx] = db; rqq[ty][tx] = qq;
    __syncthreads();
    for (int s = 8; s > 0; s >>= 1) {
        if (ty < s) {
            rdf[ty][tx] += rdf[ty + s][tx];
            rdb[ty][tx] += rdb[ty + s][tx];
            rqq[ty][tx] += rqq[ty + s][tx];
        }
        __syncthreads();
    }
    if (ty == 0) {
        float nq = sqrtf(rqq[0][tx]);
        float simf = 10.f * rdf[0][tx] / fmaxf(nq * nf, 1e-8f);
        float simb = 10.f * rdb[0][tx] / fmaxf(nq * nb, 1e-8f);
        dsim[b * Npx + p] = simf - simb;
        invn[b * Npx + p] = 1.f / nq;
    }
    // write Ft rows (coalesced dword stores, conflict-free LDS dword reads)
    int w = t >> 6, lane = t & 63;           // 8 waves
    unsigned short* FtB = Ft + (size_t)b * Npx * Cch;
    for (int pr = w; pr < 32; pr += 8) {
        unsigned* dst = (unsigned*)(FtB + (size_t)(p0 + pr) * Cch);
        #pragma unroll
        for (int it = 0; it < 4; it++) {
            int d = it * 64 + lane;
            dst[d] = *(const unsigned*)&S[pr][d * 2];
        }
    }
}

// ---------------- 3: select + compact, wave-shfl scan ----------------
// grid (2, Bsz), block 1024 (16 waves). x=0: fg, x=1: bg
__global__ void __launch_bounds__(1024) k_selcompact(const float* __restrict__ dsim,
                        const float* __restrict__ invn,
                        int* __restrict__ nsf, int* __restrict__ nsb,
                        int* __restrict__ jf, int* __restrict__ jb,
                        float* __restrict__ ivg) {
    __shared__ int wsum[16];
    int b = blockIdx.y, t = threadIdx.x;
    int lane = t & 63, w = t >> 6;
    bool isf = (blockIdx.x == 0);
    float d = dsim[b * Npx + t];
    float key = isf ? d : -d;
    float thres = isf ? 0.8472979f : 0.4054651f;   // ln(0.7/0.3), ln(0.6/0.4)
    int flag = (key > thres) ? 1 : 0;
    int x = flag;
    #pragma unroll
    for (int o = 1; o < 64; o <<= 1) {
        int y = __shfl_up(x, o);
        if (lane >= o) x += y;
    }
    if (lane == 63) wsum[w] = x;
    __syncthreads();
    int base = 0, total = 0;
    #pragma unroll
    for (int k = 0; k < 16; k++) {
        int s = wsum[k];
        if (k < w) base += s;
        total += s;
    }
    if (total == 0) {
        // cold path: top-12 fallback (lower index wins ties)
        __shared__ int   sc[Npx];
        __shared__ float v[Npx];
        __shared__ float rv[Npx];
        __shared__ int   ri[Npx];
        v[t] = key; flag = 0;
        __syncthreads();
        for (int k = 0; k < TOPK; k++) {
            rv[t] = v[t]; ri[t] = t;
            __syncthreads();
            for (int s = 512; s > 0; s >>= 1) {
                if (t < s) {
                    float a = rv[t], bb = rv[t + s];
                    int ia = ri[t], ib = ri[t + s];
                    if (bb > a || (bb == a && ib < ia)) { rv[t] = bb; ri[t] = ib; }
                }
                __syncthreads();
            }
            int win = ri[0];
            if (t == win) { flag = 1; v[t] = -INFINITY; }
            __syncthreads();
        }
        sc[t] = flag;
        __syncthreads();
        for (int off = 1; off < 1024; off <<= 1) {
            int xx = (t >= off) ? sc[t - off] : 0;
            __syncthreads();
            sc[t] += xx;
            __syncthreads();
        }
        if (flag) {
            int pos = sc[t] - 1;
            if (isf) jf[b * Npx + pos] = t;
            else {
                jb[b * Npx + pos] = t;
                ivg[b * Npx + pos] = invn[b * Npx + t];
            }
        }
        if (t == 1023) { if (isf) nsf[b] = sc[1023]; else nsb[b] = sc[1023]; }
        return;
    }
    if (flag) {
        int pos = base + x - 1;
        if (isf) jf[b * Npx + pos] = t;
        else {
            jb[b * Npx + pos] = t;
            ivg[b * Npx + pos] = invn[b * Npx + t];
        }
    }
    if (t == 0) { if (isf) nsf[b] = total; else nsb[b] = total; }
}

// ---------------- 4: fused prototypes + gather-transpose ----------------
// grid (32, 17, Bsz), block 256.
__global__ void k_mid(const float* __restrict__ fq, const unsigned short* __restrict__ Ft,
                      const int* __restrict__ jf, const int* __restrict__ nsf,
                      const int* __restrict__ jb, const int* __restrict__ nsb,
                      unsigned short* __restrict__ Fg,
                      float* __restrict__ fgp, float* __restrict__ bgp) {
    int b = blockIdx.z;
    if (blockIdx.y < 16) {
        int ns = nsb[b];
        int KC = (ns + 31) & ~31;
        int j0 = blockIdx.x * 32;
        if (j0 >= KC) return;
        int c0 = blockIdx.y * 32;
        __shared__ unsigned short tt[32][33];
        int col = threadIdx.x & 31, rr = threadIdx.x >> 5;
        const unsigned short* S = Ft + (size_t)b * Npx * Cch;
        const int* ji = jb + b * Npx;
        for (int r = rr; r < 32; r += 8) {
            int j = j0 + r;
            int src = (j < ns) ? ji[j] : ji[ns - 1];   // pad rows: P==0 there
            tt[r][col] = S[(size_t)src * Cch + c0 + col];
        }
        __syncthreads();
        unsigned short* D = Fg + (size_t)b * Cch * Npx;
        for (int r = rr; r < 32; r += 8)
            D[(size_t)(c0 + r) * Npx + j0 + col] = tt[col][r];
    } else {
        if (blockIdx.x >= 16) return;
        int cb = blockIdx.x * 32;
        int tx = threadIdx.x & 31, ty = threadIdx.x >> 5;
        const float* F = fq + (size_t)b * Cch * Npx;
        for (int which = 0; which < 2; which++) {
            const int* ji = (which ? jb : jf) + b * Npx;
            int ns = (which ? nsb : nsf)[b];
            for (int g = 0; g < 4; g++) {
                int c = cb + g * 8 + ty;
                float s = 0.f;
                for (int k = tx; k < ns; k += 32) s += F[(size_t)c * Npx + ji[k]];
                #pragma unroll
                for (int o = 16; o > 0; o >>= 1) s += __shfl_down(s, o);
                if (tx == 0) (which ? bgp : fgp)[b * Cch + c] = s / (float)ns;
            }
        }
    }
}

// ---------------- 5: Gram over compacted columns (inline index gather) --------
// grid (8, 8, Bsz), block 256
__global__ void __launch_bounds__(256) k_gram_c(const unsigned short* __restrict__ Ft,
                                                const int* __restrict__ jb,
                                                const int* __restrict__ nsb,
                                                unsigned short* __restrict__ G) {
    int b = blockIdx.z;
    int ns = nsb[b];
    int KC = (ns + 31) & ~31;
    int j0 = blockIdx.y * 128;
    if (j0 >= KC) return;
    int i0 = blockIdx.x * 128;
    __shared__ unsigned short At[128][40];
    __shared__ unsigned short Bt[128][40];
    __shared__ int sji[128];
    const unsigned short* FA = Ft + (size_t)b * Npx * Cch;
    int tid = threadIdx.x;
    if (tid < 128) {
        int j = j0 + tid;
        sji[tid] = (j < ns) ? jb[b * Npx + j] : jb[b * Npx];
    }
    __syncthreads();
    int l = tid & 63, w = tid >> 6;
    int ml = l & 15, quad = l >> 4;
    int wi = (w & 1) * 64, wj = (w >> 1) * 64;
    f32x4 acc[4][4] = {};
    for (int k0 = 0; k0 < Cch; k0 += 32) {
        #pragma unroll
        for (int s = 0; s < 2; s++) {
            int idx = tid + s * 256;
            int r = idx >> 2, kc = idx & 3;
            *(uint4*)&At[r][kc * 8] = *(const uint4*)(FA + (size_t)(i0 + r) * Cch + k0 + kc * 8);
            *(uint4*)&Bt[r][kc * 8] = *(const uint4*)(FA + (size_t)sji[r] * Cch + k0 + kc * 8);
        }
        __syncthreads();
        bf16x8 af[4], bfr[4];
        #pragma unroll
        for (int u = 0; u < 4; u++) af[u] = *(const bf16x8*)&At[wi + u * 16 + ml][quad * 8];
        #pragma unroll
        for (int v = 0; v < 4; v++) bfr[v] = *(const bf16x8*)&Bt[wj + v * 16 + ml][quad * 8];
        #pragma unroll
        for (int u = 0; u < 4; u++)
            #pragma unroll
            for (int v = 0; v < 4; v++)
                acc[u][v] = __builtin_amdgcn_mfma_f32_16x16x32_bf16(af[u], bfr[v], acc[u][v], 0, 0, 0);
        __syncthreads();
    }
    unsigned short* g = G + (size_t)b * Npx * Npx;
    #pragma unroll
    for (int u = 0; u < 4; u++) {
        int i = i0 + wi + u * 16 + quad * 4;
        #pragma unroll
        for (int v = 0; v < 4; v++) {
            int j = j0 + wj + v * 16 + ml;
            #pragma unroll
            for (int r = 0; r < 4; r++)
                g[(size_t)(i + r) * Npx + j] = f2bf(acc[u][v][r]);
        }
    }
}

// ---------------- 6: wave-per-row compact softmax (no max pass) ----------------
// grid (Npx/4, Bsz), block 256 (4 waves, one row each)
__global__ void k_softmax_w(unsigned short* __restrict__ G, const float* __restrict__ invn,
                            const float* __restrict__ ivg, const int* __restrict__ nsb) {
    int b = blockIdx.y;
    int ns = nsb[b];
    int KC = (ns + 31) & ~31;
    int w = threadIdx.x >> 6, l = threadIdx.x & 63;
    int i = blockIdx.x * 4 + w;
    unsigned short* row = G + ((size_t)b * Npx + i) * Npx;
    const float* iv = ivg + (size_t)b * Npx;
    float ivi = 2.f * invn[b * Npx + i];
    float vals[16];
    float sum = 0.f;
    #pragma unroll
    for (int k = 0; k < 16; k++) {
        int jc = k * 64 + l;
        float e = 0.f;
        if (jc < ns) e = expf(bf2f(row[jc]) * ivi * iv[jc]);
        vals[k] = e;
        sum += e;
    }
    #pragma unroll
    for (int o = 32; o > 0; o >>= 1) sum += __shfl_xor(sum, o);
    float inv = 1.f / sum;
    #pragma unroll
    for (int k = 0; k < 16; k++) {
        int jc = k * 64 + l;
        if (jc < KC) row[jc] = f2bf(vals[k] * inv);   // [ns,KC) -> 0
    }
}

// ---------------- 7: PV over compacted K -> localh (bf16, [c][i]) ----------------
// grid (8, 8, Bsz), block 256
__global__ void __launch_bounds__(256) k_pv_c(const unsigned short* __restrict__ Fg,
                                              const unsigned short* __restrict__ A,
                                              const int* __restrict__ nsb,
                                              unsigned short* __restrict__ Dout) {
    int b = blockIdx.z;
    int KC = (nsb[b] + 31) & ~31;
    __shared__ unsigned short At[64][40];
    __shared__ unsigned short Bt[128][40];
    int i0 = blockIdx.x * 128, c0 = blockIdx.y * 64;
    const unsigned short* F = Fg + (size_t)b * Cch * Npx;
    const unsigned short* Ar = A + (size_t)b * Npx * Npx;
    int tid = threadIdx.x;
    int l = tid & 63, w = tid >> 6;
    int ml = l & 15, quad = l >> 4;
    int wm = (w & 1) * 32, wn = (w >> 1) * 64;
    f32x4 acc[2][4] = {};
    for (int j0 = 0; j0 < KC; j0 += 32) {
        {
            int r = tid >> 2, kc = tid & 3;
            *(uint4*)&At[r][kc * 8] = *(const uint4*)(F + (size_t)(c0 + r) * Npx + j0 + kc * 8);
        }
        #pragma unroll
        for (int s = 0; s < 2; s++) {
            int idx = tid + s * 256;
            int r = idx >> 2, kc = idx & 3;
            *(uint4*)&Bt[r][kc * 8] = *(const uint4*)(Ar + (size_t)(i0 + r) * Npx + j0 + kc * 8);
        }
        __syncthreads();
        bf16x8 af[2], bfr[4];
        #pragma unroll
        for (int u = 0; u < 2; u++) af[u] = *(const bf16x8*)&At[wm + u * 16 + ml][quad * 8];
        #pragma unroll
        for (int v = 0; v < 4; v++) bfr[v] = *(const bf16x8*)&Bt[wn + v * 16 + ml][quad * 8];
        #pragma unroll
        for (int u = 0; u < 2; u++)
            #pragma unroll
            for (int v = 0; v < 4; v++)
                acc[u][v] = __builtin_amdgcn_mfma_f32_16x16x32_bf16(af[u], bfr[v], acc[u][v], 0, 0, 0);
        __syncthreads();
    }
    unsigned short* D = Dout + (size_t)b * Cch * Npx;
    #pragma unroll
    for (int u = 0; u < 2; u++) {
        int c = c0 + wm + u * 16 + quad * 4;
        #pragma unroll
        for (int v = 0; v < 4; v++) {
            int i = i0 + wn + v * 16 + ml;
            #pragma unroll
            for (int r = 0; r < 4; r++)
                D[(size_t)(c + r) * Npx + i] = f2bf(acc[u][v][r]);
        }
    }
}

// ---------------- 8: final dual similarity (block 512: 16 thr/pixel) ----------
// grid (Npx/32, Bsz), block 512: 32 pixels/block, 16 threads/pixel (32 ch each)
__global__ void __launch_bounds__(512) k_out(const unsigned short* __restrict__ Ft,
                      const float* __restrict__ FP,
                      const float* __restrict__ fgp, const float* __restrict__ bgp,
                      const unsigned short* __restrict__ localh, float* __restrict__ out) {
    __shared__ float sFP1[Cch], sBG[Cch], s8[8];
    __shared__ float rdf[16][32], rdb[16][32], rqq[16][32], rnb[16][32];
    int b = blockIdx.y, t = threadIdx.x;
    int tx = t & 31, ty = t >> 5;           // ty in [0,16)
    int p = blockIdx.x * 32 + tx;
    sFP1[t] = 0.5f * FP[b * Cch + t] + 0.5f * fgp[b * Cch + t];
    sBG[t] = 0.3f * bgp[b * Cch + t];
    __syncthreads();
    float nf = sqrtf(block_sum512(sFP1[t] * sFP1[t], s8));
    const unsigned short* qr = Ft + ((size_t)b * Npx + p) * Cch;
    const unsigned short* lo = localh + (size_t)b * Cch * Npx + p;
    float df = 0.f, db = 0.f, qq = 0.f, nb2 = 0.f;
    int c0 = ty * 32;
    #pragma unroll
    for (int cc = 0; cc < 4; cc++) {
        bf16x8 qv = *(const bf16x8*)&qr[c0 + cc * 8];
        #pragma unroll
        for (int e = 0; e < 8; e++) {
            int c = c0 + cc * 8 + e;
            float v = bf2f((unsigned short)qv[e]);
            float bp1 = sBG[c] + 0.7f * bf2f(lo[(size_t)c * Npx]);
            df += v * sFP1[c];
            db += v * bp1;
            qq += v * v;
            nb2 += bp1 * bp1;
        }
    }
    rdf[ty][tx] = df; rdb[ty][tx] = db; rqq[ty][tx] = qq; rnb[ty][tx] = nb2;
    __syncthreads();
    for (int s = 8; s > 0; s >>= 1) {
        if (ty < s) {
            rdf[ty][tx] += rdf[ty + s][tx];
            rdb[ty][tx] += rdb[ty + s][tx];
            rqq[ty][tx] += rqq[ty + s][tx];
            rnb[ty][tx] += rnb[ty + s][tx];
        }
        __syncthreads();
    }
    if (ty == 0) {
        float nq = sqrtf(rqq[0][tx]);
        float sf = 10.f * rdf[0][tx] / fmaxf(nq * nf, 1e-8f);
        float sb = 10.f * rdb[0][tx] / fmaxf(nq * sqrtf(rnb[0][tx]), 1e-8f);
        out[((size_t)b * 2) * Npx + p] = sb;
        out[((size_t)b * 2 + 1) * Npx + p] = sf;
    }
}

extern "C" void kernel_launch(void* const* d_in, const int* in_sizes, int n_in,
                              void* d_out, int out_size, void* d_ws, size_t ws_size,
                              hipStream_t stream) {
    const float* fq = (const float*)d_in[0];
    const float* sf = (const float*)d_in[1];
    const int* mask = (const int*)d_in[2];
    float* out = (float*)d_out;

    float* ws = (float*)d_ws;
    float* FP    = ws;                        // B*C
    float* BP    = FP + Bsz * Cch;
    float* fgp   = BP + Bsz * Cch;
    float* bgp   = fgp + Bsz * Cch;
    float* dsim  = bgp + Bsz * Cch;           // B*N
    float* invn  = dsim + Bsz * Npx;
    float* ivg   = invn + Bsz * Npx;
    int*   nsf   = (int*)(ivg + Bsz * Npx);   // 8
    int*   nsb   = nsf + 8;                   // 8
    int*   jf    = nsb + 8;                   // B*N
    int*   jb    = jf + Bsz * Npx;            // B*N
    unsigned short* Ft     = (unsigned short*)(jb + Bsz * Npx);          // 8 MB [i][c]
    unsigned short* Fg     = Ft + (size_t)Bsz * Npx * Cch;               // 8 MB [c][jc]
    unsigned short* Gb     = Fg + (size_t)Bsz * Cch * Npx;               // 16 MB
    unsigned short* localh = Gb + (size_t)Bsz * Npx * Npx;               // 8 MB bf16 [c][i]

    k_pool<<<dim3(Cch, Bsz), 256, 0, stream>>>(sf, mask, FP, BP);
    k_predcast<<<dim3(Npx / 32, Bsz), 512, 0, stream>>>(fq, FP, BP, dsim, invn, Ft);
    k_selcompact<<<dim3(2, Bsz), 1024, 0, stream>>>(dsim, invn, nsf, nsb, jf, jb, ivg);
    k_mid<<<dim3(32, 17, Bsz), 256, 0, stream>>>(fq, Ft, jf, nsf, jb, nsb, Fg, fgp, bgp);
    k_gram_c<<<dim3(8, 8, Bsz), 256, 0, stream>>>(Ft, jb, nsb, Gb);
    k_softmax_w<<<dim3(Npx / 4, Bsz), 256, 0, stream>>>(Gb, invn, ivg, nsb);
    k_pv_c<<<dim3(8, 8, Bsz), 256, 0, stream>>>(Fg, Gb, nsb, localh);
    k_out<<<dim3(Npx / 32, Bsz), 512, 0, stream>>>(Ft, FP, fgp, bgp, localh, out);
}